// Round 9
// baseline (131.008 us; speedup 1.0000x reference)
//
#include <hip/hip_runtime.h>
#include <math.h>

#define DIMC 192
#define DI   384
#define DS   16
#define LTOK 4096
#define NCH  256
#define CLEN 16
#define NLANE (DI*DS)   // 6144
#define L2E  1.4426950408889634f
#define LN2  0.6931471805599453f

typedef __attribute__((ext_vector_type(8))) short    bf16x8;
typedef __attribute__((ext_vector_type(8))) unsigned short u16x8;
typedef __attribute__((ext_vector_type(4))) float    f32x4;

__device__ __forceinline__ float EXP2(float x) { return __builtin_amdgcn_exp2f(x); }
__device__ __forceinline__ float RCP(float x)  { return __builtin_amdgcn_rcpf(x); }
__device__ __forceinline__ float LOG2(float x) { return __builtin_amdgcn_logf(x); }

__device__ __forceinline__ float sigmoidf_(float x) { return RCP(1.f + EXP2(-x * L2E)); }
__device__ __forceinline__ float siluf_(float x)    { return x * RCP(1.f + EXP2(-x * L2E)); }
__device__ __forceinline__ unsigned short f2bf(float f) {
    unsigned int u = __float_as_uint(f);
    u += 0x7FFFu + ((u >> 16) & 1u);
    return (unsigned short)(u >> 16);
}
__device__ __forceinline__ float bf2f(unsigned short b) {
    return __uint_as_float(((unsigned int)b) << 16);
}

// ---- fused pool+ln1 (blocks 0..255) + one-time weight prep (blocks 256..287) ----
__global__ __launch_bounds__(256) void poolln_kernel(const float* __restrict__ x,
                                                     const float* __restrict__ g,
                                                     const float* __restrict__ bb,
                                                     const float* __restrict__ W_in,
                                                     const float* __restrict__ W_out,
                                                     const float* __restrict__ W_xp,
                                                     const float* __restrict__ A_log,
                                                     float* __restrict__ tokens,
                                                     unsigned short* __restrict__ ytok,
                                                     unsigned short* __restrict__ W_in_bf,
                                                     unsigned short* __restrict__ W_out_bf,
                                                     unsigned short* __restrict__ W_xp_pad,
                                                     float* __restrict__ A2pre) {
    int blk = blockIdx.x;
    int tid = threadIdx.x;
    if (blk >= 256) {   // prep path
        int id = (blk - 256) * 256 + tid;     // 0..8191
        for (int i = id; i < 768 * 192; i += 8192) W_in_bf[i] = f2bf(W_in[i]);
        for (int i = id; i < 192 * 384; i += 8192) W_out_bf[i] = f2bf(W_out[i]);
        for (int i = id; i < 64 * 384; i += 8192) {
            int row = i / 384;
            W_xp_pad[i] = (row < 44) ? f2bf(W_xp[i]) : (unsigned short)0;
        }
        for (int i = id; i < NLANE; i += 8192) A2pre[i] = -expf(A_log[i]) * L2E;
        return;
    }
    int t = blk >> 4, hs = blk & 15;
    int grp = tid >> 4, ws = tid & 15;
    __shared__ float P[16 * 196];
    __shared__ float ms[16], rs[16];
    #pragma unroll
    for (int k = 0; k < 12; ++k) {
        int c = grp + (k << 4);
        const float* base = x + ((size_t)(c * 16 + t) * 64 + hs * 4) * 64 + ws * 4;
        float s = 0.f;
        #pragma unroll
        for (int i = 0; i < 4; ++i) {
            float4 v = *(const float4*)(base + i * 64);
            s += v.x + v.y + v.z + v.w;
        }
        P[ws * 196 + c] = s * 0.0625f;
    }
    __syncthreads();
    float s1 = 0.f, s2 = 0.f;
    #pragma unroll
    for (int k = 0; k < 12; ++k) {
        float v = P[grp * 196 + ws + 16 * k];
        s1 += v; s2 += v * v;
    }
    s1 += __shfl_xor(s1, 1); s2 += __shfl_xor(s2, 1);
    s1 += __shfl_xor(s1, 2); s2 += __shfl_xor(s2, 2);
    s1 += __shfl_xor(s1, 4); s2 += __shfl_xor(s2, 4);
    s1 += __shfl_xor(s1, 8); s2 += __shfl_xor(s2, 8);
    if (ws == 0) {
        float m = s1 * (1.f / 192.f);
        ms[grp] = m;
        rs[grp] = rsqrtf(s2 * (1.f / 192.f) - m * m + 1e-5f);
    }
    __syncthreads();
    int l0 = t * 256 + hs * 16;
    for (int e = tid; e < 16 * 192; e += 256) {
        int w2 = e / 192, c = e - w2 * 192;
        float v = P[w2 * 196 + c];
        float val = (v - ms[w2]) * rs[w2] * g[c] + bb[c];
        tokens[(size_t)(l0 + w2) * DIMC + c] = v;
        ytok[(size_t)(l0 + w2) * DIMC + c] = f2bf(val);
    }
}

// ---- MFMA GEMM (xz = ytok @ W_in^T): 64x64 tiles, K=192 ----
template<int K>
__global__ __launch_bounds__(256) void gemm_mfma(const unsigned short* __restrict__ A,
                                                 const unsigned short* __restrict__ Wb,
                                                 float* __restrict__ Cout,
                                                 int N) {
    constexpr int KT = 192;
    constexpr int KP = KT + 8;
    __shared__ unsigned short As[64 * KP];
    __shared__ unsigned short Bs[64 * KP];
    int bm = blockIdx.y * 64;
    int bn = blockIdx.x * 64;
    int tid = threadIdx.x;
    int lane = tid & 63, w = tid >> 6;
    int wr = w >> 1, wc = w & 1;
    int r16 = lane & 15, h = lane >> 4;
    f32x4 acc[2][2] = {};
    for (int kt = 0; kt < K; kt += KT) {
        for (int c = tid; c < 64 * (KT / 8); c += 256) {
            int row = c / (KT / 8), col = (c % (KT / 8)) * 8;
            *(u16x8*)&As[row * KP + col] = *(const u16x8*)(A + (size_t)(bm + row) * K + kt + col);
            *(u16x8*)&Bs[row * KP + col] = *(const u16x8*)(Wb + (size_t)(bn + row) * K + kt + col);
        }
        __syncthreads();
        #pragma unroll
        for (int k0 = 0; k0 < KT; k0 += 32) {
            bf16x8 a0 = *(const bf16x8*)&As[(wr * 32 + r16)      * KP + k0 + 8 * h];
            bf16x8 a1 = *(const bf16x8*)&As[(wr * 32 + 16 + r16) * KP + k0 + 8 * h];
            bf16x8 b0 = *(const bf16x8*)&Bs[(wc * 32 + r16)      * KP + k0 + 8 * h];
            bf16x8 b1 = *(const bf16x8*)&Bs[(wc * 32 + 16 + r16) * KP + k0 + 8 * h];
            acc[0][0] = __builtin_amdgcn_mfma_f32_16x16x32_bf16(a0, b0, acc[0][0], 0, 0, 0);
            acc[0][1] = __builtin_amdgcn_mfma_f32_16x16x32_bf16(a0, b1, acc[0][1], 0, 0, 0);
            acc[1][0] = __builtin_amdgcn_mfma_f32_16x16x32_bf16(a1, b0, acc[1][0], 0, 0, 0);
            acc[1][1] = __builtin_amdgcn_mfma_f32_16x16x32_bf16(a1, b1, acc[1][1], 0, 0, 0);
        }
        __syncthreads();
    }
    #pragma unroll
    for (int fm = 0; fm < 2; ++fm)
        #pragma unroll
        for (int fn = 0; fn < 2; ++fn)
            #pragma unroll
            for (int i = 0; i < 4; ++i) {
                int r = bm + wr * 32 + fm * 16 + h * 4 + i;
                int cc = bn + wc * 32 + fn * 16 + r16;
                Cout[(size_t)r * N + cc] = acc[fm][fn][i];
            }
}

// ---- conv(k=4 causal)+silu -> xsb, then MFMA x_dbl = xs @ W_xp_pad^T (N=64) ----
__global__ __launch_bounds__(256) void convxdbl(const float* __restrict__ xz,
                                                const float* __restrict__ conv_w,
                                                const float* __restrict__ conv_b,
                                                const unsigned short* __restrict__ Wxp,
                                                unsigned short* __restrict__ xsb,
                                                float* __restrict__ x_dbl) {
    int l0 = blockIdx.x * 16;
    int tid = threadIdx.x;
    __shared__ unsigned short As[16 * 392];
    __shared__ float xd[16 * 64];
    for (int e = tid * 2; e < 16 * 384; e += 512) {
        int row = e / 384, d = e - row * 384;
        int l = l0 + row;
        float ax = conv_b[d], ay = conv_b[d + 1];
        #pragma unroll
        for (int k = 0; k < 4; ++k) {
            int ll = l - 3 + k;
            if (ll >= 0) {
                float2 v = *(const float2*)(xz + (size_t)ll * 768 + d);
                ax = fmaf(conv_w[d * 4 + k],       v.x, ax);
                ay = fmaf(conv_w[(d + 1) * 4 + k], v.y, ay);
            }
        }
        ushort2 b2;
        b2.x = f2bf(siluf_(ax));
        b2.y = f2bf(siluf_(ay));
        *(ushort2*)&As[row * 392 + d] = b2;
        *(ushort2*)(xsb + (size_t)l * 384 + d) = b2;
    }
    __syncthreads();
    int lane = tid & 63, w = tid >> 6;
    int r16 = lane & 15, hh = lane >> 4;
    f32x4 acc = {};
    #pragma unroll
    for (int k0 = 0; k0 < 384; k0 += 32) {
        bf16x8 a = *(const bf16x8*)&As[r16 * 392 + k0 + 8 * hh];
        bf16x8 b = *(const bf16x8*)(Wxp + (size_t)(w * 16 + r16) * 384 + k0 + 8 * hh);
        acc = __builtin_amdgcn_mfma_f32_16x16x32_bf16(a, b, acc, 0, 0, 0);
    }
    #pragma unroll
    for (int i = 0; i < 4; ++i) xd[(hh * 4 + i) * 64 + w * 16 + r16] = acc[i];
    __syncthreads();
    {
        int e = tid * 4;
        int row = e >> 6, col = e & 63;
        *(float4*)(x_dbl + (size_t)(l0 + row) * 64 + col) = *(const float4*)&xd[e];
    }
}

// ---- scan1: compute dt in-block from x_dbl; local scan + y_local + Dloc + summaries ----
// block 256 = (sq 4) x (dl 64); grid (6 d-groups, NCH chunks)
__global__ __launch_bounds__(256) void scan1(const float* __restrict__ x_dbl,
                                             const unsigned short* __restrict__ xsb,
                                             const float* __restrict__ W_dt,
                                             const float* __restrict__ b_dt,
                                             const float* __restrict__ A2pre,
                                             float* __restrict__ chA,
                                             float* __restrict__ chB,
                                             float* __restrict__ Dloc,
                                             unsigned short* __restrict__ yloc) {
    int tid = threadIdx.x;
    int dg = blockIdx.x;          // 0..5
    int c  = blockIdx.y;          // 0..NCH-1
    __shared__ float xdblS[16 * 48];
    __shared__ float wdtS[64 * 13];
    __shared__ float dtS[16][64];
    __shared__ unsigned short xsS[16][64];
    for (int i = tid; i < 768; i += 256) {
        int row = i / 48, col = i - row * 48;
        xdblS[i] = x_dbl[(size_t)(c * 16 + row) * 64 + col];
    }
    for (int i = tid; i < 768; i += 256) {
        int dl_ = i / 12, r = i - dl_ * 12;
        wdtS[dl_ * 13 + r] = W_dt[(size_t)dg * 768 + i];
    }
    for (int i = tid; i < 1024; i += 256) {
        int row = i >> 6, dl_ = i & 63;
        xsS[row][dl_] = xsb[(size_t)(c * 16 + row) * 384 + dg * 64 + dl_];
    }
    __syncthreads();
    {
        int dl_ = tid & 63;
        float bd = b_dt[dg * 64 + dl_];
        #pragma unroll
        for (int i2 = 0; i2 < 4; ++i2) {
            int row = (tid >> 6) + 4 * i2;
            float s = bd;
            #pragma unroll
            for (int r = 0; r < 12; ++r)
                s = fmaf(xdblS[row * 48 + r], wdtS[dl_ * 13 + r], s);
            dtS[row][dl_] = (s > 20.f) ? s : LOG2(1.f + EXP2(s * L2E)) * LN2;
        }
    }
    __syncthreads();
    int sq = tid & 3, dl = tid >> 2;
    int d = dg * 64 + dl;
    float4 a4 = *(const float4*)(A2pre + (size_t)d * DS + sq * 4);
    float A2[4] = {a4.x, a4.y, a4.z, a4.w};
    float h[4] = {};
    float dts = 0.f;
    #pragma unroll
    for (int i = 0; i < CLEN; ++i) {
        int l = c * CLEN + i;
        float dtv = dtS[i][dl];
        float xv  = bf2f(xsS[i][dl]);
        float dtx = dtv * xv;
        dts += dtv;
        float y = 0.f;
        #pragma unroll
        for (int u = 0; u < 4; ++u) {
            float a = EXP2(dtv * A2[u]);
            h[u] = fmaf(a, h[u], dtx * xdblS[i * 48 + 12 + sq * 4 + u]);
            y = fmaf(h[u], xdblS[i * 48 + 28 + sq * 4 + u], y);
        }
        y += __shfl_xor(y, 1);
        y += __shfl_xor(y, 2);
        if (sq == 0) {
            yloc[(size_t)l * DI + d] = f2bf(y);
            Dloc[(size_t)l * DI + d] = dts;
        }
    }
    size_t base = (size_t)c * NLANE + d * DS + sq * 4;
    float4 pa, pb;
    pa.x = EXP2(dts * A2[0]); pa.y = EXP2(dts * A2[1]);
    pa.z = EXP2(dts * A2[2]); pa.w = EXP2(dts * A2[3]);
    pb.x = h[0]; pb.y = h[1]; pb.z = h[2]; pb.w = h[3];
    *(float4*)&chA[base] = pa;
    *(float4*)&chB[base] = pb;
}

// ---- scan2p: hierarchical parallel inter-chunk scan ----
__global__ __launch_bounds__(256) void scan2p(const float* __restrict__ chA,
                                              const float* __restrict__ chB,
                                              float* __restrict__ hst) {
    int tid = threadIdx.x;
    int ll = tid & 15;
    int g  = tid >> 4;
    int lane = blockIdx.x * 16 + ll;
    float a[16], b[16];
    #pragma unroll
    for (int i = 0; i < 16; ++i) {
        int c = g * 16 + i;
        a[i] = chA[(size_t)c * NLANE + lane];
        b[i] = chB[(size_t)c * NLANE + lane];
    }
    float Ath = 1.f, Bth = 0.f;
    #pragma unroll
    for (int i = 0; i < 16; ++i) {
        Bth = fmaf(a[i], Bth, b[i]);
        Ath *= a[i];
    }
    __shared__ float sA[16][17], sB[16][17];
    sA[g][ll] = Ath; sB[g][ll] = Bth;
    __syncthreads();
    #pragma unroll
    for (int step = 1; step < 16; step <<= 1) {
        float pA = 1.f, pB = 0.f;
        if (g >= step) { pA = sA[g - step][ll]; pB = sB[g - step][ll]; }
        __syncthreads();
        if (g >= step) {
            float cA = sA[g][ll], cB = sB[g][ll];
            sA[g][ll] = cA * pA;
            sB[g][ll] = fmaf(cA, pB, cB);
        }
        __syncthreads();
    }
    float h = (g == 0) ? 0.f : sB[g - 1][ll];
    #pragma unroll
    for (int i = 0; i < 16; ++i) {
        int c = g * 16 + i;
        hst[(size_t)c * NLANE + lane] = h;
        h = fmaf(a[i], h, b[i]);
    }
}

// ---- scan3fix: elementwise fix-up + gate. block 256 = 16 l x 16 d; grid (24, NCH) ----
__global__ __launch_bounds__(256) void scan3fix(const float* __restrict__ hst,
                                                const float* __restrict__ Dloc,
                                                const float* __restrict__ x_dbl,
                                                const float* __restrict__ A2pre,
                                                const unsigned short* __restrict__ xsb,
                                                const float* __restrict__ xz,
                                                const float* __restrict__ Dvec,
                                                unsigned short* __restrict__ ybuf) {
    int dg = blockIdx.x;
    int c  = blockIdx.y;
    int tid = threadIdx.x;
    int ll = tid >> 4, dl = tid & 15;
    int d = dg * 16 + dl;
    int l = c * 16 + ll;
    __shared__ float hpS[16][17];
    __shared__ float A2S[16][17];
    __shared__ float CsS[256];
    {
        int dd = tid >> 4, ss = tid & 15;
        hpS[dd][ss] = hst[(size_t)c * NLANE + dg * 256 + tid];
        A2S[dd][ss] = A2pre[(size_t)dg * 256 + tid];
        CsS[tid]    = x_dbl[(size_t)(c * 16 + dd) * 64 + 28 + ss];
    }
    __syncthreads();
    float Dl = Dloc[(size_t)l * DI + d];
    float y  = bf2f(ybuf[(size_t)l * DI + d]);
    float xv = bf2f(xsb[(size_t)l * DI + d]);
    float z  = xz[(size_t)l * 768 + 384 + d];
    #pragma unroll
    for (int s = 0; s < 16; ++s) {
        float e = EXP2(A2S[dl][s] * Dl);
        y = fmaf(CsS[ll * 16 + s] * e, hpS[dl][s], y);
    }
    float val = (y + xv * Dvec[d]) * siluf_(z);
    ybuf[(size_t)l * DI + d] = f2bf(val);
}

// ---- gemmln: gout = ybuf @ W_out^T (64x192 tile, full N) + residual + LN2 -> o5 ----
__global__ __launch_bounds__(256) void gemmln(const unsigned short* __restrict__ A,
                                              const unsigned short* __restrict__ Wb,
                                              const float* __restrict__ tokens,
                                              const float* __restrict__ g,
                                              const float* __restrict__ bb,
                                              float* __restrict__ o5) {
    constexpr int K = 384, KT = 192, KP = KT + 8;
    __shared__ char smem[(64 + 192) * KP * 2];     // 102.4 KB, reused for P
    unsigned short* As = (unsigned short*)smem;
    unsigned short* Bs = As + 64 * KP;
    float* P = (float*)smem;                       // [64][193] after MFMA
    __shared__ float ms[64], rs[64];
    int bm = blockIdx.x * 64;
    int tid = threadIdx.x;
    int lane = tid & 63, w = tid >> 6;
    int r16 = lane & 15, hh = lane >> 4;
    f32x4 acc[12] = {};
    for (int kt = 0; kt < K; kt += KT) {
        for (int cc = tid; cc < 64 * (KT / 8); cc += 256) {
            int row = cc / (KT / 8), col = (cc % (KT / 8)) * 8;
            *(u16x8*)&As[row * KP + col] = *(const u16x8*)(A + (size_t)(bm + row) * K + kt + col);
        }
        for (int cc = tid; cc < 192 * (KT / 8); cc += 256) {
            int row = cc / (KT / 8), col = (cc % (KT / 8)) * 8;
            *(u16x8*)&Bs[row * KP + col] = *(const u16x8*)(Wb + (size_t)row * K + kt + col);
        }
        __syncthreads();
        #pragma unroll
        for (int k0 = 0; k0 < KT; k0 += 32) {
            bf16x8 a = *(const bf16x8*)&As[(w * 16 + r16) * KP + k0 + 8 * hh];
            #pragma unroll
            for (int j = 0; j < 12; ++j) {
                bf16x8 b = *(const bf16x8*)&Bs[(j * 16 + r16) * KP + k0 + 8 * hh];
                acc[j] = __builtin_amdgcn_mfma_f32_16x16x32_bf16(a, b, acc[j], 0, 0, 0);
            }
        }
        __syncthreads();
    }
    for (int e = tid; e < 64 * 192; e += 256) {
        int row = e / 192, col = e - row * 192;
        P[row * 193 + col] = tokens[(size_t)(bm + row) * DIMC + col];
    }
    __syncthreads();
    #pragma unroll
    for (int j = 0; j < 12; ++j)
        #pragma unroll
        for (int i = 0; i < 4; ++i)
            P[(w * 16 + hh * 4 + i) * 193 + j * 16 + r16] += acc[j][i];
    __syncthreads();
    {
        int tk = tid >> 2, q = tid & 3;
        float s1 = 0.f, s2 = 0.f;
        #pragma unroll
        for (int u = 0; u < 48; ++u) {
            float v = P[tk * 193 + q * 48 + u];
            s1 += v; s2 += v * v;
        }
        s1 += __shfl_xor(s1, 1); s2 += __shfl_xor(s2, 1);
        s1 += __shfl_xor(s1, 2); s2 += __shfl_xor(s2, 2);
        if (q == 0) {
            float m = s1 * (1.f / 192.f);
            ms[tk] = m;
            rs[tk] = rsqrtf(s2 * (1.f / 192.f) - m * m + 1e-5f);
        }
    }
    __syncthreads();
    int t = bm >> 8;
    int sp0 = bm & 255;
    for (int e = tid; e < 64 * 192; e += 256) {
        int cch = e >> 6, row = e & 63;
        float val = (P[row * 193 + cch] - ms[row]) * rs[row] * g[cch] + bb[cch];
        o5[(size_t)cch * 4096 + t * 256 + sp0 + row] = val;
    }
}

// ---- upfft: per (c,t) block — recompute channel weight (pooled DFT) + upsample ----
__global__ __launch_bounds__(256) void upfft(const float* __restrict__ o5,
                                             const float* __restrict__ x,
                                             float* __restrict__ out) {
    int blk = blockIdx.x;          // c*16 + t
    int c = blk >> 4, t = blk & 15;
    int tid = threadIdx.x;
    __shared__ float pl[256];
    __shared__ float pooled[16];
    __shared__ float mag[8];
    __shared__ float wgt_s;
    int wv = tid >> 6, lane = tid & 63;
    #pragma unroll
    for (int rr = 0; rr < 4; ++rr) {
        int r = wv * 4 + rr;
        float s = 0.f;
        #pragma unroll
        for (int u = 0; u < 4; ++u) {
            float v = o5[(size_t)c * 4096 + r * 256 + lane + u * 64];
            s += v;
            if (r == t) pl[lane + u * 64] = v;
        }
        s += __shfl_xor(s, 1); s += __shfl_xor(s, 2); s += __shfl_xor(s, 4);
        s += __shfl_xor(s, 8); s += __shfl_xor(s, 16); s += __shfl_xor(s, 32);
        if (lane == 0) pooled[r] = s * (1.f / 256.f);
    }
    __syncthreads();
    if (tid >= 1 && tid <= 7) {
        int k = tid;
        float re = 0.f, im = 0.f;
        for (int tt = 0; tt < 16; ++tt) {
            float ang = -0.39269908169872414f * (float)(k * tt);
            re = fmaf(pooled[tt], cosf(ang), re);
            im = fmaf(pooled[tt], sinf(ang), im);
        }
        mag[k] = sqrtf(re * re + im * im);
    }
    __syncthreads();
    if (tid == 0) {
        float m = 0.f;
        for (int k = 1; k <= 7; ++k) m += mag[k];
        wgt_s = sigmoidf_(m * (1.f / 7.f));
    }
    __syncthreads();
    float wc = wgt_s;
    size_t planeoff = (size_t)blk * 4096;
    #pragma unroll
    for (int p = 0; p < 4; ++p) {
        int px4 = p * 256 + tid;       // w-quad index 0..1023
        int k = px4 & 15;
        int hrow = px4 >> 4;           // 0..63
        float sh = hrow * 0.25f - 0.375f;
        int h0 = (int)floorf(sh); float fh = sh - (float)h0;
        int h0c = min(max(h0, 0), 15), h1c = min(max(h0 + 1, 0), 15);
        int cm = max(k - 1, 0), cp = min(k + 1, 15);
        float r0m = pl[h0c * 16 + cm], r00 = pl[h0c * 16 + k], r0p = pl[h0c * 16 + cp];
        float r1m = pl[h1c * 16 + cm], r10 = pl[h1c * 16 + k], r1p = pl[h1c * 16 + cp];
        float gh = 1.f - fh;
        float vm = r0m * gh + r1m * fh;
        float v0 = r00 * gh + r10 * fh;
        float vp = r0p * gh + r1p * fh;
        size_t off = planeoff + (size_t)px4 * 4;
        float4 xv = *(const float4*)(x + off);
        float4 o;
        o.x = (vm * 0.375f + v0 * 0.625f) * wc * sigmoidf_(xv.x);
        o.y = (vm * 0.125f + v0 * 0.875f) * wc * sigmoidf_(xv.y);
        o.z = (v0 * 0.875f + vp * 0.125f) * wc * sigmoidf_(xv.z);
        o.w = (v0 * 0.625f + vp * 0.375f) * wc * sigmoidf_(xv.w);
        *(float4*)(out + off) = o;
    }
}

extern "C" void kernel_launch(void* const* d_in, const int* in_sizes, int n_in,
                              void* d_out, int out_size, void* d_ws, size_t ws_size,
                              hipStream_t stream) {
    const float* x      = (const float*)d_in[0];
    const float* ln1_g  = (const float*)d_in[1];
    const float* ln1_b  = (const float*)d_in[2];
    const float* ln2_g  = (const float*)d_in[3];
    const float* ln2_b  = (const float*)d_in[4];
    const float* W_in   = (const float*)d_in[5];
    const float* conv_w = (const float*)d_in[6];
    const float* conv_b = (const float*)d_in[7];
    const float* W_xp   = (const float*)d_in[8];
    const float* W_dt   = (const float*)d_in[9];
    const float* b_dt   = (const float*)d_in[10];
    const float* A_log  = (const float*)d_in[11];
    const float* Dvec   = (const float*)d_in[12];
    const float* W_out  = (const float*)d_in[13];
    float* out = (float*)d_out;

    float* ws = (float*)d_ws;
    float* tokens = ws;  ws += (size_t)LTOK * DIMC;
    float* xz     = ws;  ws += (size_t)LTOK * 768;
    float* x_dbl  = ws;  ws += (size_t)LTOK * 64;
    float* chA    = ws;  ws += (size_t)NLANE * NCH;
    float* chB    = ws;  ws += (size_t)NLANE * NCH;
    float* hst    = ws;  ws += (size_t)NLANE * NCH;
    float* Dloc   = ws;  ws += (size_t)LTOK * DI;
    float* o5     = ws;  ws += (size_t)DIMC * LTOK;
    float* A2pre  = ws;  ws += NLANE;
    unsigned short* ytok     = (unsigned short*)ws;  ws += (size_t)LTOK * DIMC / 2;
    unsigned short* ybuf     = (unsigned short*)ws;  ws += (size_t)LTOK * DI / 2;
    unsigned short* xsb      = (unsigned short*)ws;  ws += (size_t)LTOK * DI / 2;
    unsigned short* W_in_bf  = (unsigned short*)ws;  ws += (size_t)768 * 192 / 2;
    unsigned short* W_out_bf = (unsigned short*)ws;  ws += (size_t)192 * 384 / 2;
    unsigned short* W_xp_pad = (unsigned short*)ws;  ws += (size_t)64 * 384 / 2;

    poolln_kernel<<<288, 256, 0, stream>>>(x, ln1_g, ln1_b, W_in, W_out, W_xp, A_log,
                                           tokens, ytok, W_in_bf, W_out_bf, W_xp_pad, A2pre);
    gemm_mfma<192><<<dim3(12, 64), 256, 0, stream>>>(ytok, W_in_bf, xz, 768);
    convxdbl<<<256, 256, 0, stream>>>(xz, conv_w, conv_b, W_xp_pad, xsb, x_dbl);
    scan1<<<dim3(6, NCH), 256, 0, stream>>>(x_dbl, xsb, W_dt, b_dt, A2pre, chA, chB, Dloc, ybuf);
    scan2p<<<NLANE / 16, 256, 0, stream>>>(chA, chB, hst);
    scan3fix<<<dim3(24, NCH), 256, 0, stream>>>(hst, Dloc, x_dbl, A2pre, xsb, xz, Dvec, ybuf);
    gemmln<<<64, 256, 0, stream>>>(ybuf, W_out_bf, tokens, ln2_g, ln2_b, o5);
    upfft<<<3072, 256, 0, stream>>>(o5, x, out);
}

// Round 10
// 125.496 us; speedup vs baseline: 1.0439x; 1.0439x over previous
//
#include <hip/hip_runtime.h>
#include <math.h>

#define DIMC 192
#define DI   384
#define DS   16
#define LTOK 4096
#define NCH  256
#define CLEN 16
#define NLANE (DI*DS)   // 6144
#define L2E  1.4426950408889634f
#define LN2  0.6931471805599453f

typedef __attribute__((ext_vector_type(8))) short    bf16x8;
typedef __attribute__((ext_vector_type(8))) unsigned short u16x8;
typedef __attribute__((ext_vector_type(4))) float    f32x4;

__device__ __forceinline__ float EXP2(float x) { return __builtin_amdgcn_exp2f(x); }
__device__ __forceinline__ float RCP(float x)  { return __builtin_amdgcn_rcpf(x); }
__device__ __forceinline__ float LOG2(float x) { return __builtin_amdgcn_logf(x); }

__device__ __forceinline__ float sigmoidf_(float x) { return RCP(1.f + EXP2(-x * L2E)); }
__device__ __forceinline__ float siluf_(float x)    { return x * RCP(1.f + EXP2(-x * L2E)); }
__device__ __forceinline__ unsigned short f2bf(float f) {
    unsigned int u = __float_as_uint(f);
    u += 0x7FFFu + ((u >> 16) & 1u);
    return (unsigned short)(u >> 16);
}
__device__ __forceinline__ float bf2f(unsigned short b) {
    return __uint_as_float(((unsigned int)b) << 16);
}

// ---- fused pool+ln1 (blocks 0..255) + one-time weight prep (blocks 256..287) ----
__global__ __launch_bounds__(256) void poolln_kernel(const float* __restrict__ x,
                                                     const float* __restrict__ g,
                                                     const float* __restrict__ bb,
                                                     const float* __restrict__ W_in,
                                                     const float* __restrict__ W_out,
                                                     const float* __restrict__ W_xp,
                                                     const float* __restrict__ A_log,
                                                     float* __restrict__ tokens,
                                                     unsigned short* __restrict__ ytok,
                                                     unsigned short* __restrict__ W_in_bf,
                                                     unsigned short* __restrict__ W_out_bf,
                                                     unsigned short* __restrict__ W_xp_pad,
                                                     float* __restrict__ A2pre) {
    int blk = blockIdx.x;
    int tid = threadIdx.x;
    if (blk >= 256) {   // prep path
        int id = (blk - 256) * 256 + tid;     // 0..8191
        for (int i = id; i < 768 * 192; i += 8192) W_in_bf[i] = f2bf(W_in[i]);
        for (int i = id; i < 192 * 384; i += 8192) W_out_bf[i] = f2bf(W_out[i]);
        for (int i = id; i < 64 * 384; i += 8192) {
            int row = i / 384;
            W_xp_pad[i] = (row < 44) ? f2bf(W_xp[i]) : (unsigned short)0;
        }
        for (int i = id; i < NLANE; i += 8192) A2pre[i] = -expf(A_log[i]) * L2E;
        return;
    }
    int t = blk >> 4, hs = blk & 15;
    int grp = tid >> 4, ws = tid & 15;
    __shared__ float P[16 * 196];
    __shared__ float ms[16], rs[16];
    #pragma unroll
    for (int k = 0; k < 12; ++k) {
        int c = grp + (k << 4);
        const float* base = x + ((size_t)(c * 16 + t) * 64 + hs * 4) * 64 + ws * 4;
        float s = 0.f;
        #pragma unroll
        for (int i = 0; i < 4; ++i) {
            float4 v = *(const float4*)(base + i * 64);
            s += v.x + v.y + v.z + v.w;
        }
        P[ws * 196 + c] = s * 0.0625f;
    }
    __syncthreads();
    float s1 = 0.f, s2 = 0.f;
    #pragma unroll
    for (int k = 0; k < 12; ++k) {
        float v = P[grp * 196 + ws + 16 * k];
        s1 += v; s2 += v * v;
    }
    s1 += __shfl_xor(s1, 1); s2 += __shfl_xor(s2, 1);
    s1 += __shfl_xor(s1, 2); s2 += __shfl_xor(s2, 2);
    s1 += __shfl_xor(s1, 4); s2 += __shfl_xor(s2, 4);
    s1 += __shfl_xor(s1, 8); s2 += __shfl_xor(s2, 8);
    if (ws == 0) {
        float m = s1 * (1.f / 192.f);
        ms[grp] = m;
        rs[grp] = rsqrtf(s2 * (1.f / 192.f) - m * m + 1e-5f);
    }
    __syncthreads();
    int l0 = t * 256 + hs * 16;
    for (int e = tid; e < 16 * 192; e += 256) {
        int w2 = e / 192, c = e - w2 * 192;
        float v = P[w2 * 196 + c];
        float val = (v - ms[w2]) * rs[w2] * g[c] + bb[c];
        tokens[(size_t)(l0 + w2) * DIMC + c] = v;
        ytok[(size_t)(l0 + w2) * DIMC + c] = f2bf(val);
    }
}

// ---- MFMA GEMM (xz = ytok @ W_in^T): 64x64 tiles, K=192 ----
template<int K>
__global__ __launch_bounds__(256) void gemm_mfma(const unsigned short* __restrict__ A,
                                                 const unsigned short* __restrict__ Wb,
                                                 float* __restrict__ Cout,
                                                 int N) {
    constexpr int KT = 192;
    constexpr int KP = KT + 8;
    __shared__ unsigned short As[64 * KP];
    __shared__ unsigned short Bs[64 * KP];
    int bm = blockIdx.y * 64;
    int bn = blockIdx.x * 64;
    int tid = threadIdx.x;
    int lane = tid & 63, w = tid >> 6;
    int wr = w >> 1, wc = w & 1;
    int r16 = lane & 15, h = lane >> 4;
    f32x4 acc[2][2] = {};
    for (int kt = 0; kt < K; kt += KT) {
        for (int c = tid; c < 64 * (KT / 8); c += 256) {
            int row = c / (KT / 8), col = (c % (KT / 8)) * 8;
            *(u16x8*)&As[row * KP + col] = *(const u16x8*)(A + (size_t)(bm + row) * K + kt + col);
            *(u16x8*)&Bs[row * KP + col] = *(const u16x8*)(Wb + (size_t)(bn + row) * K + kt + col);
        }
        __syncthreads();
        #pragma unroll
        for (int k0 = 0; k0 < KT; k0 += 32) {
            bf16x8 a0 = *(const bf16x8*)&As[(wr * 32 + r16)      * KP + k0 + 8 * h];
            bf16x8 a1 = *(const bf16x8*)&As[(wr * 32 + 16 + r16) * KP + k0 + 8 * h];
            bf16x8 b0 = *(const bf16x8*)&Bs[(wc * 32 + r16)      * KP + k0 + 8 * h];
            bf16x8 b1 = *(const bf16x8*)&Bs[(wc * 32 + 16 + r16) * KP + k0 + 8 * h];
            acc[0][0] = __builtin_amdgcn_mfma_f32_16x16x32_bf16(a0, b0, acc[0][0], 0, 0, 0);
            acc[0][1] = __builtin_amdgcn_mfma_f32_16x16x32_bf16(a0, b1, acc[0][1], 0, 0, 0);
            acc[1][0] = __builtin_amdgcn_mfma_f32_16x16x32_bf16(a1, b0, acc[1][0], 0, 0, 0);
            acc[1][1] = __builtin_amdgcn_mfma_f32_16x16x32_bf16(a1, b1, acc[1][1], 0, 0, 0);
        }
        __syncthreads();
    }
    #pragma unroll
    for (int fm = 0; fm < 2; ++fm)
        #pragma unroll
        for (int fn = 0; fn < 2; ++fn)
            #pragma unroll
            for (int i = 0; i < 4; ++i) {
                int r = bm + wr * 32 + fm * 16 + h * 4 + i;
                int cc = bn + wc * 32 + fn * 16 + r16;
                Cout[(size_t)r * N + cc] = acc[fm][fn][i];
            }
}

// ---- conv(k=4 causal)+silu -> xsb, then MFMA x_dbl = xs @ W_xp_pad^T (N=64) ----
__global__ __launch_bounds__(256) void convxdbl(const float* __restrict__ xz,
                                                const float* __restrict__ conv_w,
                                                const float* __restrict__ conv_b,
                                                const unsigned short* __restrict__ Wxp,
                                                unsigned short* __restrict__ xsb,
                                                float* __restrict__ x_dbl) {
    int l0 = blockIdx.x * 16;
    int tid = threadIdx.x;
    __shared__ unsigned short As[16 * 392];
    __shared__ float xd[16 * 64];
    for (int e = tid * 2; e < 16 * 384; e += 512) {
        int row = e / 384, d = e - row * 384;
        int l = l0 + row;
        float ax = conv_b[d], ay = conv_b[d + 1];
        #pragma unroll
        for (int k = 0; k < 4; ++k) {
            int ll = l - 3 + k;
            if (ll >= 0) {
                float2 v = *(const float2*)(xz + (size_t)ll * 768 + d);
                ax = fmaf(conv_w[d * 4 + k],       v.x, ax);
                ay = fmaf(conv_w[(d + 1) * 4 + k], v.y, ay);
            }
        }
        ushort2 b2;
        b2.x = f2bf(siluf_(ax));
        b2.y = f2bf(siluf_(ay));
        *(ushort2*)&As[row * 392 + d] = b2;
        *(ushort2*)(xsb + (size_t)l * 384 + d) = b2;
    }
    __syncthreads();
    int lane = tid & 63, w = tid >> 6;
    int r16 = lane & 15, hh = lane >> 4;
    f32x4 acc = {};
    #pragma unroll
    for (int k0 = 0; k0 < 384; k0 += 32) {
        bf16x8 a = *(const bf16x8*)&As[r16 * 392 + k0 + 8 * hh];
        bf16x8 b = *(const bf16x8*)(Wxp + (size_t)(w * 16 + r16) * 384 + k0 + 8 * hh);
        acc = __builtin_amdgcn_mfma_f32_16x16x32_bf16(a, b, acc, 0, 0, 0);
    }
    #pragma unroll
    for (int i = 0; i < 4; ++i) xd[(hh * 4 + i) * 64 + w * 16 + r16] = acc[i];
    __syncthreads();
    {
        int e = tid * 4;
        int row = e >> 6, col = e & 63;
        *(float4*)(x_dbl + (size_t)(l0 + row) * 64 + col) = *(const float4*)&xd[e];
    }
}

// ---- scan1: compute dt in-block from x_dbl; local scan + y_local + Dloc + summaries ----
// block 256 = (sq 4) x (dl 64); grid (6 d-groups, NCH chunks)
__global__ __launch_bounds__(256) void scan1(const float* __restrict__ x_dbl,
                                             const unsigned short* __restrict__ xsb,
                                             const float* __restrict__ W_dt,
                                             const float* __restrict__ b_dt,
                                             const float* __restrict__ A2pre,
                                             float* __restrict__ chA,
                                             float* __restrict__ chB,
                                             float* __restrict__ Dloc,
                                             unsigned short* __restrict__ yloc) {
    int tid = threadIdx.x;
    int dg = blockIdx.x;          // 0..5
    int c  = blockIdx.y;          // 0..NCH-1
    __shared__ float xdblS[16 * 48];
    __shared__ float wdtS[64 * 13];
    __shared__ float dtS[16][64];
    __shared__ unsigned short xsS[16][64];
    for (int i = tid; i < 768; i += 256) {
        int row = i / 48, col = i - row * 48;
        xdblS[i] = x_dbl[(size_t)(c * 16 + row) * 64 + col];
    }
    for (int i = tid; i < 768; i += 256) {
        int dl_ = i / 12, r = i - dl_ * 12;
        wdtS[dl_ * 13 + r] = W_dt[(size_t)dg * 768 + i];
    }
    for (int i = tid; i < 1024; i += 256) {
        int row = i >> 6, dl_ = i & 63;
        xsS[row][dl_] = xsb[(size_t)(c * 16 + row) * 384 + dg * 64 + dl_];
    }
    __syncthreads();
    {
        int dl_ = tid & 63;
        float bd = b_dt[dg * 64 + dl_];
        #pragma unroll
        for (int i2 = 0; i2 < 4; ++i2) {
            int row = (tid >> 6) + 4 * i2;
            float s = bd;
            #pragma unroll
            for (int r = 0; r < 12; ++r)
                s = fmaf(xdblS[row * 48 + r], wdtS[dl_ * 13 + r], s);
            dtS[row][dl_] = (s > 20.f) ? s : LOG2(1.f + EXP2(s * L2E)) * LN2;
        }
    }
    __syncthreads();
    int sq = tid & 3, dl = tid >> 2;
    int d = dg * 64 + dl;
    float4 a4 = *(const float4*)(A2pre + (size_t)d * DS + sq * 4);
    float A2[4] = {a4.x, a4.y, a4.z, a4.w};
    float h[4] = {};
    float dts = 0.f;
    #pragma unroll
    for (int i = 0; i < CLEN; ++i) {
        int l = c * CLEN + i;
        float dtv = dtS[i][dl];
        float xv  = bf2f(xsS[i][dl]);
        float dtx = dtv * xv;
        dts += dtv;
        float y = 0.f;
        #pragma unroll
        for (int u = 0; u < 4; ++u) {
            float a = EXP2(dtv * A2[u]);
            h[u] = fmaf(a, h[u], dtx * xdblS[i * 48 + 12 + sq * 4 + u]);
            y = fmaf(h[u], xdblS[i * 48 + 28 + sq * 4 + u], y);
        }
        y += __shfl_xor(y, 1);
        y += __shfl_xor(y, 2);
        if (sq == 0) {
            yloc[(size_t)l * DI + d] = f2bf(y);
            Dloc[(size_t)l * DI + d] = dts;
        }
    }
    size_t base = (size_t)c * NLANE + d * DS + sq * 4;
    float4 pa, pb;
    pa.x = EXP2(dts * A2[0]); pa.y = EXP2(dts * A2[1]);
    pa.z = EXP2(dts * A2[2]); pa.w = EXP2(dts * A2[3]);
    pb.x = h[0]; pb.y = h[1]; pb.z = h[2]; pb.w = h[3];
    *(float4*)&chA[base] = pa;
    *(float4*)&chB[base] = pb;
}

// ---- scan2p: hierarchical parallel inter-chunk scan ----
__global__ __launch_bounds__(256) void scan2p(const float* __restrict__ chA,
                                              const float* __restrict__ chB,
                                              float* __restrict__ hst) {
    int tid = threadIdx.x;
    int ll = tid & 15;
    int g  = tid >> 4;
    int lane = blockIdx.x * 16 + ll;
    float a[16], b[16];
    #pragma unroll
    for (int i = 0; i < 16; ++i) {
        int c = g * 16 + i;
        a[i] = chA[(size_t)c * NLANE + lane];
        b[i] = chB[(size_t)c * NLANE + lane];
    }
    float Ath = 1.f, Bth = 0.f;
    #pragma unroll
    for (int i = 0; i < 16; ++i) {
        Bth = fmaf(a[i], Bth, b[i]);
        Ath *= a[i];
    }
    __shared__ float sA[16][17], sB[16][17];
    sA[g][ll] = Ath; sB[g][ll] = Bth;
    __syncthreads();
    #pragma unroll
    for (int step = 1; step < 16; step <<= 1) {
        float pA = 1.f, pB = 0.f;
        if (g >= step) { pA = sA[g - step][ll]; pB = sB[g - step][ll]; }
        __syncthreads();
        if (g >= step) {
            float cA = sA[g][ll], cB = sB[g][ll];
            sA[g][ll] = cA * pA;
            sB[g][ll] = fmaf(cA, pB, cB);
        }
        __syncthreads();
    }
    float h = (g == 0) ? 0.f : sB[g - 1][ll];
    #pragma unroll
    for (int i = 0; i < 16; ++i) {
        int c = g * 16 + i;
        hst[(size_t)c * NLANE + lane] = h;
        h = fmaf(a[i], h, b[i]);
    }
}

// ---- scan3fix: elementwise fix-up + gate. block 256 = 16 l x 16 d; grid (24, NCH) ----
__global__ __launch_bounds__(256) void scan3fix(const float* __restrict__ hst,
                                                const float* __restrict__ Dloc,
                                                const float* __restrict__ x_dbl,
                                                const float* __restrict__ A2pre,
                                                const unsigned short* __restrict__ xsb,
                                                const float* __restrict__ xz,
                                                const float* __restrict__ Dvec,
                                                unsigned short* __restrict__ ybuf) {
    int dg = blockIdx.x;
    int c  = blockIdx.y;
    int tid = threadIdx.x;
    int ll = tid >> 4, dl = tid & 15;
    int d = dg * 16 + dl;
    int l = c * 16 + ll;
    __shared__ float hpS[16][17];
    __shared__ float A2S[16][17];
    __shared__ float CsS[256];
    {
        int dd = tid >> 4, ss = tid & 15;
        hpS[dd][ss] = hst[(size_t)c * NLANE + dg * 256 + tid];
        A2S[dd][ss] = A2pre[(size_t)dg * 256 + tid];
        CsS[tid]    = x_dbl[(size_t)(c * 16 + dd) * 64 + 28 + ss];
    }
    __syncthreads();
    float Dl = Dloc[(size_t)l * DI + d];
    float y  = bf2f(ybuf[(size_t)l * DI + d]);
    float xv = bf2f(xsb[(size_t)l * DI + d]);
    float z  = xz[(size_t)l * 768 + 384 + d];
    #pragma unroll
    for (int s = 0; s < 16; ++s) {
        float e = EXP2(A2S[dl][s] * Dl);
        y = fmaf(CsS[ll * 16 + s] * e, hpS[dl][s], y);
    }
    float val = (y + xv * Dvec[d]) * siluf_(z);
    ybuf[(size_t)l * DI + d] = f2bf(val);
}

// ---- gemmln: gout = ybuf @ W_out^T (M=16, full N=192) + residual + LN2 -> o5 ----
// grid 256 blocks x 256 threads; LDS ~56 KB -> 2 blocks/CU
__global__ __launch_bounds__(256) void gemmln(const unsigned short* __restrict__ A,
                                              const unsigned short* __restrict__ Wb,
                                              const float* __restrict__ tokens,
                                              const float* __restrict__ g,
                                              const float* __restrict__ bb,
                                              float* __restrict__ o5) {
    constexpr int K = 384, KT = 96, KP = KT + 8;   // 104
    __shared__ unsigned short As[16 * KP];          // 3.3 KB
    __shared__ unsigned short Bs[192 * KP];         // 39.9 KB
    __shared__ float P[16 * 193];                   // 12.4 KB
    __shared__ float ms[16], rs[16];
    int bm = blockIdx.x * 16;
    int tid = threadIdx.x;
    int lane = tid & 63, w = tid >> 6;              // wave w owns n-tiles w*3..w*3+2
    int r16 = lane & 15, hh = lane >> 4;
    f32x4 acc[3] = {};
    for (int kt = 0; kt < K; kt += KT) {
        if (tid < 192) {   // A tile: 16 rows x 12 chunks
            int row = tid / 12, col = (tid % 12) * 8;
            *(u16x8*)&As[row * KP + col] = *(const u16x8*)(A + (size_t)(bm + row) * K + kt + col);
        }
        for (int cc = tid; cc < 192 * 12; cc += 256) {
            int row = cc / 12, col = (cc % 12) * 8;
            *(u16x8*)&Bs[row * KP + col] = *(const u16x8*)(Wb + (size_t)row * K + kt + col);
        }
        __syncthreads();
        #pragma unroll
        for (int k0 = 0; k0 < KT; k0 += 32) {
            bf16x8 a = *(const bf16x8*)&As[r16 * KP + k0 + 8 * hh];
            #pragma unroll
            for (int j = 0; j < 3; ++j) {
                bf16x8 b = *(const bf16x8*)&Bs[((w * 3 + j) * 16 + r16) * KP + k0 + 8 * hh];
                acc[j] = __builtin_amdgcn_mfma_f32_16x16x32_bf16(a, b, acc[j], 0, 0, 0);
            }
        }
        __syncthreads();
    }
    // P = tokens tile (residual)
    for (int e = tid; e < 16 * 192; e += 256) {
        int row = e / 192, col = e - row * 192;
        P[row * 193 + col] = tokens[(size_t)(bm + row) * DIMC + col];
    }
    __syncthreads();
    #pragma unroll
    for (int j = 0; j < 3; ++j)
        #pragma unroll
        for (int i = 0; i < 4; ++i)
            P[(hh * 4 + i) * 193 + (w * 3 + j) * 16 + r16] += acc[j][i];
    __syncthreads();
    // LN stats: 16 threads per token, 12 elems each
    {
        int tk = tid >> 4, q = tid & 15;
        float s1 = 0.f, s2 = 0.f;
        #pragma unroll
        for (int u = 0; u < 12; ++u) {
            float v = P[tk * 193 + q * 12 + u];
            s1 += v; s2 += v * v;
        }
        s1 += __shfl_xor(s1, 1); s2 += __shfl_xor(s2, 1);
        s1 += __shfl_xor(s1, 2); s2 += __shfl_xor(s2, 2);
        s1 += __shfl_xor(s1, 4); s2 += __shfl_xor(s2, 4);
        s1 += __shfl_xor(s1, 8); s2 += __shfl_xor(s2, 8);
        if (q == 0) {
            float m = s1 * (1.f / 192.f);
            ms[tk] = m;
            rs[tk] = rsqrtf(s2 * (1.f / 192.f) - m * m + 1e-5f);
        }
    }
    __syncthreads();
    int t = bm >> 8;
    int sp0 = bm & 255;
    for (int e = tid; e < 16 * 192; e += 256) {
        int cch = e >> 4, row = e & 15;
        float val = (P[row * 193 + cch] - ms[row]) * rs[row] * g[cch] + bb[cch];
        o5[(size_t)cch * 4096 + t * 256 + sp0 + row] = val;
    }
}

// ---- upfft: per (c,t) block — recompute channel weight (pooled DFT) + upsample ----
__global__ __launch_bounds__(256) void upfft(const float* __restrict__ o5,
                                             const float* __restrict__ x,
                                             float* __restrict__ out) {
    int blk = blockIdx.x;          // c*16 + t
    int c = blk >> 4, t = blk & 15;
    int tid = threadIdx.x;
    __shared__ float pl[256];
    __shared__ float pooled[16];
    __shared__ float mag[8];
    __shared__ float wgt_s;
    int wv = tid >> 6, lane = tid & 63;
    #pragma unroll
    for (int rr = 0; rr < 4; ++rr) {
        int r = wv * 4 + rr;
        float s = 0.f;
        #pragma unroll
        for (int u = 0; u < 4; ++u) {
            float v = o5[(size_t)c * 4096 + r * 256 + lane + u * 64];
            s += v;
            if (r == t) pl[lane + u * 64] = v;
        }
        s += __shfl_xor(s, 1); s += __shfl_xor(s, 2); s += __shfl_xor(s, 4);
        s += __shfl_xor(s, 8); s += __shfl_xor(s, 16); s += __shfl_xor(s, 32);
        if (lane == 0) pooled[r] = s * (1.f / 256.f);
    }
    __syncthreads();
    if (tid >= 1 && tid <= 7) {
        int k = tid;
        float re = 0.f, im = 0.f;
        for (int tt = 0; tt < 16; ++tt) {
            float ang = -0.39269908169872414f * (float)(k * tt);
            re = fmaf(pooled[tt], cosf(ang), re);
            im = fmaf(pooled[tt], sinf(ang), im);
        }
        mag[k] = sqrtf(re * re + im * im);
    }
    __syncthreads();
    if (tid == 0) {
        float m = 0.f;
        for (int k = 1; k <= 7; ++k) m += mag[k];
        wgt_s = sigmoidf_(m * (1.f / 7.f));
    }
    __syncthreads();
    float wc = wgt_s;
    size_t planeoff = (size_t)blk * 4096;
    #pragma unroll
    for (int p = 0; p < 4; ++p) {
        int px4 = p * 256 + tid;       // w-quad index 0..1023
        int k = px4 & 15;
        int hrow = px4 >> 4;           // 0..63
        float sh = hrow * 0.25f - 0.375f;
        int h0 = (int)floorf(sh); float fh = sh - (float)h0;
        int h0c = min(max(h0, 0), 15), h1c = min(max(h0 + 1, 0), 15);
        int cm = max(k - 1, 0), cp = min(k + 1, 15);
        float r0m = pl[h0c * 16 + cm], r00 = pl[h0c * 16 + k], r0p = pl[h0c * 16 + cp];
        float r1m = pl[h1c * 16 + cm], r10 = pl[h1c * 16 + k], r1p = pl[h1c * 16 + cp];
        float gh = 1.f - fh;
        float vm = r0m * gh + r1m * fh;
        float v0 = r00 * gh + r10 * fh;
        float vp = r0p * gh + r1p * fh;
        size_t off = planeoff + (size_t)px4 * 4;
        float4 xv = *(const float4*)(x + off);
        float4 o;
        o.x = (vm * 0.375f + v0 * 0.625f) * wc * sigmoidf_(xv.x);
        o.y = (vm * 0.125f + v0 * 0.875f) * wc * sigmoidf_(xv.y);
        o.z = (v0 * 0.875f + vp * 0.125f) * wc * sigmoidf_(xv.z);
        o.w = (v0 * 0.625f + vp * 0.375f) * wc * sigmoidf_(xv.w);
        *(float4*)(out + off) = o;
    }
}

extern "C" void kernel_launch(void* const* d_in, const int* in_sizes, int n_in,
                              void* d_out, int out_size, void* d_ws, size_t ws_size,
                              hipStream_t stream) {
    const float* x      = (const float*)d_in[0];
    const float* ln1_g  = (const float*)d_in[1];
    const float* ln1_b  = (const float*)d_in[2];
    const float* ln2_g  = (const float*)d_in[3];
    const float* ln2_b  = (const float*)d_in[4];
    const float* W_in   = (const float*)d_in[5];
    const float* conv_w = (const float*)d_in[6];
    const float* conv_b = (const float*)d_in[7];
    const float* W_xp   = (const float*)d_in[8];
    const float* W_dt   = (const float*)d_in[9];
    const float* b_dt   = (const float*)d_in[10];
    const float* A_log  = (const float*)d_in[11];
    const float* Dvec   = (const float*)d_in[12];
    const float* W_out  = (const float*)d_in[13];
    float* out = (float*)d_out;

    float* ws = (float*)d_ws;
    float* tokens = ws;  ws += (size_t)LTOK * DIMC;
    float* xz     = ws;  ws += (size_t)LTOK * 768;
    float* x_dbl  = ws;  ws += (size_t)LTOK * 64;
    float* chA    = ws;  ws += (size_t)NLANE * NCH;
    float* chB    = ws;  ws += (size_t)NLANE * NCH;
    float* hst    = ws;  ws += (size_t)NLANE * NCH;
    float* Dloc   = ws;  ws += (size_t)LTOK * DI;
    float* o5     = ws;  ws += (size_t)DIMC * LTOK;
    float* A2pre  = ws;  ws += NLANE;
    unsigned short* ytok     = (unsigned short*)ws;  ws += (size_t)LTOK * DIMC / 2;
    unsigned short* ybuf     = (unsigned short*)ws;  ws += (size_t)LTOK * DI / 2;
    unsigned short* xsb      = (unsigned short*)ws;  ws += (size_t)LTOK * DI / 2;
    unsigned short* W_in_bf  = (unsigned short*)ws;  ws += (size_t)768 * 192 / 2;
    unsigned short* W_out_bf = (unsigned short*)ws;  ws += (size_t)192 * 384 / 2;
    unsigned short* W_xp_pad = (unsigned short*)ws;  ws += (size_t)64 * 384 / 2;

    poolln_kernel<<<288, 256, 0, stream>>>(x, ln1_g, ln1_b, W_in, W_out, W_xp, A_log,
                                           tokens, ytok, W_in_bf, W_out_bf, W_xp_pad, A2pre);
    gemm_mfma<192><<<dim3(12, 64), 256, 0, stream>>>(ytok, W_in_bf, xz, 768);
    convxdbl<<<256, 256, 0, stream>>>(xz, conv_w, conv_b, W_xp_pad, xsb, x_dbl);
    scan1<<<dim3(6, NCH), 256, 0, stream>>>(x_dbl, xsb, W_dt, b_dt, A2pre, chA, chB, Dloc, ybuf);
    scan2p<<<NLANE / 16, 256, 0, stream>>>(chA, chB, hst);
    scan3fix<<<dim3(24, NCH), 256, 0, stream>>>(hst, Dloc, x_dbl, A2pre, xsb, xz, Dvec, ybuf);
    gemmln<<<256, 256, 0, stream>>>(ybuf, W_out_bf, tokens, ln2_g, ln2_b, o5);
    upfft<<<3072, 256, 0, stream>>>(o5, x, out);
}

// Round 11
// 110.927 us; speedup vs baseline: 1.1810x; 1.1313x over previous
//
#include <hip/hip_runtime.h>
#include <math.h>

#define DIMC 192
#define DI   384
#define DS   16
#define LTOK 4096
#define NCH  256
#define CLEN 16
#define NLANE (DI*DS)   // 6144
#define L2E  1.4426950408889634f
#define LN2  0.6931471805599453f

typedef __attribute__((ext_vector_type(8))) short    bf16x8;
typedef __attribute__((ext_vector_type(8))) unsigned short u16x8;
typedef __attribute__((ext_vector_type(4))) float    f32x4;

__device__ __forceinline__ float EXP2(float x) { return __builtin_amdgcn_exp2f(x); }
__device__ __forceinline__ float RCP(float x)  { return __builtin_amdgcn_rcpf(x); }
__device__ __forceinline__ float LOG2(float x) { return __builtin_amdgcn_logf(x); }

__device__ __forceinline__ float sigmoidf_(float x) { return RCP(1.f + EXP2(-x * L2E)); }
__device__ __forceinline__ float siluf_(float x)    { return x * RCP(1.f + EXP2(-x * L2E)); }
__device__ __forceinline__ unsigned short f2bf(float f) {
    unsigned int u = __float_as_uint(f);
    u += 0x7FFFu + ((u >> 16) & 1u);
    return (unsigned short)(u >> 16);
}
__device__ __forceinline__ float bf2f(unsigned short b) {
    return __uint_as_float(((unsigned int)b) << 16);
}

// ---- fused pool+ln1 (blocks 0..255) + one-time weight prep (blocks 256..287) ----
__global__ __launch_bounds__(256) void poolln_kernel(const float* __restrict__ x,
                                                     const float* __restrict__ g,
                                                     const float* __restrict__ bb,
                                                     const float* __restrict__ W_in,
                                                     const float* __restrict__ W_out,
                                                     const float* __restrict__ W_xp,
                                                     const float* __restrict__ A_log,
                                                     float* __restrict__ tokens,
                                                     unsigned short* __restrict__ ytok,
                                                     unsigned short* __restrict__ W_in_bf,
                                                     unsigned short* __restrict__ W_out_bf,
                                                     unsigned short* __restrict__ W_xp_pad,
                                                     float* __restrict__ A2pre) {
    int blk = blockIdx.x;
    int tid = threadIdx.x;
    if (blk >= 256) {   // prep path
        int id = (blk - 256) * 256 + tid;     // 0..8191
        for (int i = id; i < 768 * 192; i += 8192) W_in_bf[i] = f2bf(W_in[i]);
        for (int i = id; i < 192 * 384; i += 8192) W_out_bf[i] = f2bf(W_out[i]);
        for (int i = id; i < 64 * 384; i += 8192) {
            int row = i / 384;
            W_xp_pad[i] = (row < 44) ? f2bf(W_xp[i]) : (unsigned short)0;
        }
        for (int i = id; i < NLANE; i += 8192) A2pre[i] = -expf(A_log[i]) * L2E;
        return;
    }
    int t = blk >> 4, hs = blk & 15;
    int grp = tid >> 4, ws = tid & 15;
    __shared__ float P[16 * 196];
    __shared__ float ms[16], rs[16];
    #pragma unroll
    for (int k = 0; k < 12; ++k) {
        int c = grp + (k << 4);
        const float* base = x + ((size_t)(c * 16 + t) * 64 + hs * 4) * 64 + ws * 4;
        float s = 0.f;
        #pragma unroll
        for (int i = 0; i < 4; ++i) {
            float4 v = *(const float4*)(base + i * 64);
            s += v.x + v.y + v.z + v.w;
        }
        P[ws * 196 + c] = s * 0.0625f;
    }
    __syncthreads();
    float s1 = 0.f, s2 = 0.f;
    #pragma unroll
    for (int k = 0; k < 12; ++k) {
        float v = P[grp * 196 + ws + 16 * k];
        s1 += v; s2 += v * v;
    }
    s1 += __shfl_xor(s1, 1); s2 += __shfl_xor(s2, 1);
    s1 += __shfl_xor(s1, 2); s2 += __shfl_xor(s2, 2);
    s1 += __shfl_xor(s1, 4); s2 += __shfl_xor(s2, 4);
    s1 += __shfl_xor(s1, 8); s2 += __shfl_xor(s2, 8);
    if (ws == 0) {
        float m = s1 * (1.f / 192.f);
        ms[grp] = m;
        rs[grp] = rsqrtf(s2 * (1.f / 192.f) - m * m + 1e-5f);
    }
    __syncthreads();
    int l0 = t * 256 + hs * 16;
    for (int e = tid; e < 16 * 192; e += 256) {
        int w2 = e / 192, c = e - w2 * 192;
        float v = P[w2 * 196 + c];
        float val = (v - ms[w2]) * rs[w2] * g[c] + bb[c];
        tokens[(size_t)(l0 + w2) * DIMC + c] = v;
        ytok[(size_t)(l0 + w2) * DIMC + c] = f2bf(val);
    }
}

// ---- gemm_in: xz = ytok @ W_in^T, split epilogue -> xcb (bf16) / zsb = silu(z) bf16 ----
__global__ __launch_bounds__(256) void gemm_in(const unsigned short* __restrict__ A,
                                               const unsigned short* __restrict__ Wb,
                                               unsigned short* __restrict__ xcb,
                                               unsigned short* __restrict__ zsb) {
    constexpr int K = 192, KP = K + 8;
    __shared__ unsigned short As[64 * KP];
    __shared__ unsigned short Bs[64 * KP];
    int bm = blockIdx.y * 64;
    int bn = blockIdx.x * 64;
    int tid = threadIdx.x;
    int lane = tid & 63, w = tid >> 6;
    int wr = w >> 1, wc = w & 1;
    int r16 = lane & 15, h = lane >> 4;
    for (int c = tid; c < 64 * (K / 8); c += 256) {
        int row = c / (K / 8), col = (c % (K / 8)) * 8;
        *(u16x8*)&As[row * KP + col] = *(const u16x8*)(A + (size_t)(bm + row) * K + col);
        *(u16x8*)&Bs[row * KP + col] = *(const u16x8*)(Wb + (size_t)(bn + row) * K + col);
    }
    __syncthreads();
    f32x4 acc[2][2] = {};
    #pragma unroll
    for (int k0 = 0; k0 < K; k0 += 32) {
        bf16x8 a0 = *(const bf16x8*)&As[(wr * 32 + r16)      * KP + k0 + 8 * h];
        bf16x8 a1 = *(const bf16x8*)&As[(wr * 32 + 16 + r16) * KP + k0 + 8 * h];
        bf16x8 b0 = *(const bf16x8*)&Bs[(wc * 32 + r16)      * KP + k0 + 8 * h];
        bf16x8 b1 = *(const bf16x8*)&Bs[(wc * 32 + 16 + r16) * KP + k0 + 8 * h];
        acc[0][0] = __builtin_amdgcn_mfma_f32_16x16x32_bf16(a0, b0, acc[0][0], 0, 0, 0);
        acc[0][1] = __builtin_amdgcn_mfma_f32_16x16x32_bf16(a0, b1, acc[0][1], 0, 0, 0);
        acc[1][0] = __builtin_amdgcn_mfma_f32_16x16x32_bf16(a1, b0, acc[1][0], 0, 0, 0);
        acc[1][1] = __builtin_amdgcn_mfma_f32_16x16x32_bf16(a1, b1, acc[1][1], 0, 0, 0);
    }
    bool isz = (bn >= 384);
    #pragma unroll
    for (int fm = 0; fm < 2; ++fm)
        #pragma unroll
        for (int fn = 0; fn < 2; ++fn)
            #pragma unroll
            for (int i = 0; i < 4; ++i) {
                int r = bm + wr * 32 + fm * 16 + h * 4 + i;
                int cc = bn + wc * 32 + fn * 16 + r16;
                float v = acc[fm][fn][i];
                if (isz) zsb[(size_t)r * DI + (cc - 384)] = f2bf(siluf_(v));
                else     xcb[(size_t)r * DI + cc]         = f2bf(v);
            }
}

// ---- conv(k=4 causal)+silu -> xsb, then MFMA x_dbl = xs @ W_xp_pad^T (N=64) ----
__global__ __launch_bounds__(256) void convxdbl(const unsigned short* __restrict__ xcb,
                                                const float* __restrict__ conv_w,
                                                const float* __restrict__ conv_b,
                                                const unsigned short* __restrict__ Wxp,
                                                unsigned short* __restrict__ xsb,
                                                float* __restrict__ x_dbl) {
    int l0 = blockIdx.x * 16;
    int tid = threadIdx.x;
    __shared__ unsigned short As[16 * 392];
    __shared__ float xd[16 * 64];
    for (int e = tid * 2; e < 16 * 384; e += 512) {
        int row = e / 384, d = e - row * 384;
        int l = l0 + row;
        float ax = conv_b[d], ay = conv_b[d + 1];
        #pragma unroll
        for (int k = 0; k < 4; ++k) {
            int ll = l - 3 + k;
            if (ll >= 0) {
                ushort2 u = *(const ushort2*)(xcb + (size_t)ll * DI + d);
                ax = fmaf(conv_w[d * 4 + k],       bf2f(u.x), ax);
                ay = fmaf(conv_w[(d + 1) * 4 + k], bf2f(u.y), ay);
            }
        }
        ushort2 b2;
        b2.x = f2bf(siluf_(ax));
        b2.y = f2bf(siluf_(ay));
        *(ushort2*)&As[row * 392 + d] = b2;
        *(ushort2*)(xsb + (size_t)l * 384 + d) = b2;
    }
    __syncthreads();
    int lane = tid & 63, w = tid >> 6;
    int r16 = lane & 15, hh = lane >> 4;
    f32x4 acc = {};
    #pragma unroll
    for (int k0 = 0; k0 < 384; k0 += 32) {
        bf16x8 a = *(const bf16x8*)&As[r16 * 392 + k0 + 8 * hh];
        bf16x8 b = *(const bf16x8*)(Wxp + (size_t)(w * 16 + r16) * 384 + k0 + 8 * hh);
        acc = __builtin_amdgcn_mfma_f32_16x16x32_bf16(a, b, acc, 0, 0, 0);
    }
    #pragma unroll
    for (int i = 0; i < 4; ++i) xd[(hh * 4 + i) * 64 + w * 16 + r16] = acc[i];
    __syncthreads();
    {
        int e = tid * 4;
        int row = e >> 6, col = e & 63;
        *(float4*)(x_dbl + (size_t)(l0 + row) * 64 + col) = *(const float4*)&xd[e];
    }
}

// ---- scan1: compute dt in-block from x_dbl; local scan + y_local + Dloc + summaries ----
// block 256 = (sq 4) x (dl 64); grid (6 d-groups, NCH chunks)
__global__ __launch_bounds__(256) void scan1(const float* __restrict__ x_dbl,
                                             const unsigned short* __restrict__ xsb,
                                             const float* __restrict__ W_dt,
                                             const float* __restrict__ b_dt,
                                             const float* __restrict__ A2pre,
                                             float* __restrict__ chA,
                                             float* __restrict__ chB,
                                             float* __restrict__ Dloc,
                                             unsigned short* __restrict__ yloc) {
    int tid = threadIdx.x;
    int dg = blockIdx.x;          // 0..5
    int c  = blockIdx.y;          // 0..NCH-1
    __shared__ float xdblS[16 * 48];
    __shared__ float wdtS[64 * 13];
    __shared__ float dtS[16][64];
    __shared__ unsigned short xsS[16][64];
    for (int i = tid; i < 768; i += 256) {
        int row = i / 48, col = i - row * 48;
        xdblS[i] = x_dbl[(size_t)(c * 16 + row) * 64 + col];
    }
    for (int i = tid; i < 768; i += 256) {
        int dl_ = i / 12, r = i - dl_ * 12;
        wdtS[dl_ * 13 + r] = W_dt[(size_t)dg * 768 + i];
    }
    for (int i = tid; i < 1024; i += 256) {
        int row = i >> 6, dl_ = i & 63;
        xsS[row][dl_] = xsb[(size_t)(c * 16 + row) * 384 + dg * 64 + dl_];
    }
    __syncthreads();
    {
        int dl_ = tid & 63;
        float bd = b_dt[dg * 64 + dl_];
        #pragma unroll
        for (int i2 = 0; i2 < 4; ++i2) {
            int row = (tid >> 6) + 4 * i2;
            float s = bd;
            #pragma unroll
            for (int r = 0; r < 12; ++r)
                s = fmaf(xdblS[row * 48 + r], wdtS[dl_ * 13 + r], s);
            dtS[row][dl_] = (s > 20.f) ? s : LOG2(1.f + EXP2(s * L2E)) * LN2;
        }
    }
    __syncthreads();
    int sq = tid & 3, dl = tid >> 2;
    int d = dg * 64 + dl;
    float4 a4 = *(const float4*)(A2pre + (size_t)d * DS + sq * 4);
    float A2[4] = {a4.x, a4.y, a4.z, a4.w};
    float h[4] = {};
    float dts = 0.f;
    #pragma unroll
    for (int i = 0; i < CLEN; ++i) {
        int l = c * CLEN + i;
        float dtv = dtS[i][dl];
        float xv  = bf2f(xsS[i][dl]);
        float dtx = dtv * xv;
        dts += dtv;
        float y = 0.f;
        #pragma unroll
        for (int u = 0; u < 4; ++u) {
            float a = EXP2(dtv * A2[u]);
            h[u] = fmaf(a, h[u], dtx * xdblS[i * 48 + 12 + sq * 4 + u]);
            y = fmaf(h[u], xdblS[i * 48 + 28 + sq * 4 + u], y);
        }
        y += __shfl_xor(y, 1);
        y += __shfl_xor(y, 2);
        if (sq == 0) {
            yloc[(size_t)l * DI + d] = f2bf(y);
            Dloc[(size_t)l * DI + d] = dts;
        }
    }
    size_t base = (size_t)c * NLANE + d * DS + sq * 4;
    float4 pa, pb;
    pa.x = EXP2(dts * A2[0]); pa.y = EXP2(dts * A2[1]);
    pa.z = EXP2(dts * A2[2]); pa.w = EXP2(dts * A2[3]);
    pb.x = h[0]; pb.y = h[1]; pb.z = h[2]; pb.w = h[3];
    *(float4*)&chA[base] = pa;
    *(float4*)&chB[base] = pb;
}

// ---- scan2p: hierarchical parallel inter-chunk scan ----
__global__ __launch_bounds__(256) void scan2p(const float* __restrict__ chA,
                                              const float* __restrict__ chB,
                                              float* __restrict__ hst) {
    int tid = threadIdx.x;
    int ll = tid & 15;
    int g  = tid >> 4;
    int lane = blockIdx.x * 16 + ll;
    float a[16], b[16];
    #pragma unroll
    for (int i = 0; i < 16; ++i) {
        int c = g * 16 + i;
        a[i] = chA[(size_t)c * NLANE + lane];
        b[i] = chB[(size_t)c * NLANE + lane];
    }
    float Ath = 1.f, Bth = 0.f;
    #pragma unroll
    for (int i = 0; i < 16; ++i) {
        Bth = fmaf(a[i], Bth, b[i]);
        Ath *= a[i];
    }
    __shared__ float sA[16][17], sB[16][17];
    sA[g][ll] = Ath; sB[g][ll] = Bth;
    __syncthreads();
    #pragma unroll
    for (int step = 1; step < 16; step <<= 1) {
        float pA = 1.f, pB = 0.f;
        if (g >= step) { pA = sA[g - step][ll]; pB = sB[g - step][ll]; }
        __syncthreads();
        if (g >= step) {
            float cA = sA[g][ll], cB = sB[g][ll];
            sA[g][ll] = cA * pA;
            sB[g][ll] = fmaf(cA, pB, cB);
        }
        __syncthreads();
    }
    float h = (g == 0) ? 0.f : sB[g - 1][ll];
    #pragma unroll
    for (int i = 0; i < 16; ++i) {
        int c = g * 16 + i;
        hst[(size_t)c * NLANE + lane] = h;
        h = fmaf(a[i], h, b[i]);
    }
}

// ---- gemmscanln: per chunk c (16 tokens) — scan fix-up + gate -> ybuf LDS,
//      then GEMM ybuf @ W_out^T + residual + LN2 -> o5.  512 threads, 256 blocks ----
__global__ __launch_bounds__(512) void gemmscanln(const float* __restrict__ hst,
                                                  const float* __restrict__ Dloc,
                                                  const float* __restrict__ x_dbl,
                                                  const float* __restrict__ A2pre,
                                                  const unsigned short* __restrict__ yloc,
                                                  const unsigned short* __restrict__ xsb,
                                                  const unsigned short* __restrict__ zsb,
                                                  const float* __restrict__ Dvec,
                                                  const unsigned short* __restrict__ Wb,
                                                  const float* __restrict__ tokens,
                                                  const float* __restrict__ g,
                                                  const float* __restrict__ bb,
                                                  float* __restrict__ o5) {
    constexpr int K = 384, KT = 96, KP = KT + 8;   // 104
    __shared__ unsigned short ybufS[16 * 392];      // 12.5 KB — A operand
    __shared__ char smem2[192 * KP * 2];            // 39.9 KB — Bs, later P overlay
    unsigned short* Bs = (unsigned short*)smem2;
    float* P = (float*)smem2;                       // 16*193*4 = 12.4 KB
    __shared__ float hpS[2][16 * 17];
    __shared__ float A2S[2][16 * 17];
    __shared__ float CsS[256];
    __shared__ float ms[16], rs[16];
    int c = blockIdx.x;
    int tid = threadIdx.x;
    int half = tid >> 8, t8 = tid & 255;
    int ll = t8 >> 4, sl = t8 & 15;
    if (tid < 256) CsS[tid] = x_dbl[(size_t)(c * 16 + (tid >> 4)) * 64 + 28 + (tid & 15)];
    int l = c * 16 + ll;
    // phase 1: scan fix-up + gate, 2 d-groups per iteration
    for (int dgi = 0; dgi < 12; ++dgi) {
        int dg = dgi * 2 + half;
        hpS[half][ll * 17 + sl] = hst[(size_t)c * NLANE + dg * 256 + t8];
        A2S[half][ll * 17 + sl] = A2pre[(size_t)dg * 256 + t8];
        __syncthreads();
        int d = dg * 16 + sl;
        float Dl = Dloc[(size_t)l * DI + d];
        float y  = bf2f(yloc[(size_t)l * DI + d]);
        float xv = bf2f(xsb[(size_t)l * DI + d]);
        float zs = bf2f(zsb[(size_t)l * DI + d]);
        #pragma unroll
        for (int s = 0; s < 16; ++s) {
            float e = EXP2(A2S[half][sl * 17 + s] * Dl);
            y = fmaf(CsS[ll * 16 + s] * e, hpS[half][sl * 17 + s], y);
        }
        float val = (y + xv * Dvec[d]) * zs;
        ybufS[ll * 392 + d] = f2bf(val);
        __syncthreads();
    }
    // phase 2: GEMM (M=16, N=192, K=384), 8 waves; wave w -> n-tiles {w, 8+w(if w<4)}
    int lane = tid & 63, w = tid >> 6;
    int r16 = lane & 15, hh = lane >> 4;
    f32x4 acc0 = {}, acc1 = {};
    for (int kt = 0; kt < K; kt += KT) {
        for (int cc2 = tid; cc2 < 192 * 12; cc2 += 512) {
            int row = cc2 / 12, col = (cc2 % 12) * 8;
            *(u16x8*)&Bs[row * KP + col] = *(const u16x8*)(Wb + (size_t)row * K + kt + col);
        }
        __syncthreads();
        #pragma unroll
        for (int k0 = 0; k0 < KT; k0 += 32) {
            bf16x8 a = *(const bf16x8*)&ybufS[r16 * 392 + kt + k0 + 8 * hh];
            bf16x8 b0 = *(const bf16x8*)&Bs[(w * 16 + r16) * KP + k0 + 8 * hh];
            acc0 = __builtin_amdgcn_mfma_f32_16x16x32_bf16(a, b0, acc0, 0, 0, 0);
            if (w < 4) {
                bf16x8 b1 = *(const bf16x8*)&Bs[((8 + w) * 16 + r16) * KP + k0 + 8 * hh];
                acc1 = __builtin_amdgcn_mfma_f32_16x16x32_bf16(a, b1, acc1, 0, 0, 0);
            }
        }
        __syncthreads();
    }
    // phase 3: residual + scatter + LN + transposed o5 store
    for (int e = tid; e < 16 * 192; e += 512) {
        int row = e / 192, col = e - row * 192;
        P[row * 193 + col] = tokens[(size_t)(c * 16 + row) * DIMC + col];
    }
    __syncthreads();
    #pragma unroll
    for (int i = 0; i < 4; ++i)
        P[(hh * 4 + i) * 193 + w * 16 + r16] += acc0[i];
    if (w < 4)
        #pragma unroll
        for (int i = 0; i < 4; ++i)
            P[(hh * 4 + i) * 193 + (8 + w) * 16 + r16] += acc1[i];
    __syncthreads();
    {
        int tk = tid >> 5, q = tid & 31;
        float s1 = 0.f, s2 = 0.f;
        #pragma unroll
        for (int u = 0; u < 6; ++u) {
            float v = P[tk * 193 + q * 6 + u];
            s1 += v; s2 += v * v;
        }
        s1 += __shfl_xor(s1, 1);  s2 += __shfl_xor(s2, 1);
        s1 += __shfl_xor(s1, 2);  s2 += __shfl_xor(s2, 2);
        s1 += __shfl_xor(s1, 4);  s2 += __shfl_xor(s2, 4);
        s1 += __shfl_xor(s1, 8);  s2 += __shfl_xor(s2, 8);
        s1 += __shfl_xor(s1, 16); s2 += __shfl_xor(s2, 16);
        if (q == 0) {
            float m = s1 * (1.f / 192.f);
            ms[tk] = m;
            rs[tk] = rsqrtf(s2 * (1.f / 192.f) - m * m + 1e-5f);
        }
    }
    __syncthreads();
    int t = c >> 4;
    int sp0 = (c * 16) & 255;
    for (int e = tid; e < 16 * 192; e += 512) {
        int cch = e >> 4, row = e & 15;
        float val = (P[row * 193 + cch] - ms[row]) * rs[row] * g[cch] + bb[cch];
        o5[(size_t)cch * 4096 + t * 256 + sp0 + row] = val;
    }
}

// ---- upfft: per (c,t) block — recompute channel weight (pooled DFT) + upsample ----
__global__ __launch_bounds__(256) void upfft(const float* __restrict__ o5,
                                             const float* __restrict__ x,
                                             float* __restrict__ out) {
    int blk = blockIdx.x;          // c*16 + t
    int c = blk >> 4, t = blk & 15;
    int tid = threadIdx.x;
    __shared__ float pl[256];
    __shared__ float pooled[16];
    __shared__ float mag[8];
    __shared__ float wgt_s;
    int wv = tid >> 6, lane = tid & 63;
    #pragma unroll
    for (int rr = 0; rr < 4; ++rr) {
        int r = wv * 4 + rr;
        float s = 0.f;
        #pragma unroll
        for (int u = 0; u < 4; ++u) {
            float v = o5[(size_t)c * 4096 + r * 256 + lane + u * 64];
            s += v;
            if (r == t) pl[lane + u * 64] = v;
        }
        s += __shfl_xor(s, 1); s += __shfl_xor(s, 2); s += __shfl_xor(s, 4);
        s += __shfl_xor(s, 8); s += __shfl_xor(s, 16); s += __shfl_xor(s, 32);
        if (lane == 0) pooled[r] = s * (1.f / 256.f);
    }
    __syncthreads();
    if (tid >= 1 && tid <= 7) {
        int k = tid;
        float re = 0.f, im = 0.f;
        for (int tt = 0; tt < 16; ++tt) {
            float ang = -0.39269908169872414f * (float)(k * tt);
            re = fmaf(pooled[tt], __cosf(ang), re);
            im = fmaf(pooled[tt], __sinf(ang), im);
        }
        mag[k] = sqrtf(re * re + im * im);
    }
    __syncthreads();
    if (tid == 0) {
        float m = 0.f;
        for (int k = 1; k <= 7; ++k) m += mag[k];
        wgt_s = sigmoidf_(m * (1.f / 7.f));
    }
    __syncthreads();
    float wc = wgt_s;
    size_t planeoff = (size_t)blk * 4096;
    #pragma unroll
    for (int p = 0; p < 4; ++p) {
        int px4 = p * 256 + tid;       // w-quad index 0..1023
        int k = px4 & 15;
        int hrow = px4 >> 4;           // 0..63
        float sh = hrow * 0.25f - 0.375f;
        int h0 = (int)floorf(sh); float fh = sh - (float)h0;
        int h0c = min(max(h0, 0), 15), h1c = min(max(h0 + 1, 0), 15);
        int cm = max(k - 1, 0), cp = min(k + 1, 15);
        float r0m = pl[h0c * 16 + cm], r00 = pl[h0c * 16 + k], r0p = pl[h0c * 16 + cp];
        float r1m = pl[h1c * 16 + cm], r10 = pl[h1c * 16 + k], r1p = pl[h1c * 16 + cp];
        float gh = 1.f - fh;
        float vm = r0m * gh + r1m * fh;
        float v0 = r00 * gh + r10 * fh;
        float vp = r0p * gh + r1p * fh;
        size_t off = planeoff + (size_t)px4 * 4;
        float4 xv = *(const float4*)(x + off);
        float4 o;
        o.x = (vm * 0.375f + v0 * 0.625f) * wc * sigmoidf_(xv.x);
        o.y = (vm * 0.125f + v0 * 0.875f) * wc * sigmoidf_(xv.y);
        o.z = (v0 * 0.875f + vp * 0.125f) * wc * sigmoidf_(xv.z);
        o.w = (v0 * 0.625f + vp * 0.375f) * wc * sigmoidf_(xv.w);
        *(float4*)(out + off) = o;
    }
}

extern "C" void kernel_launch(void* const* d_in, const int* in_sizes, int n_in,
                              void* d_out, int out_size, void* d_ws, size_t ws_size,
                              hipStream_t stream) {
    const float* x      = (const float*)d_in[0];
    const float* ln1_g  = (const float*)d_in[1];
    const float* ln1_b  = (const float*)d_in[2];
    const float* ln2_g  = (const float*)d_in[3];
    const float* ln2_b  = (const float*)d_in[4];
    const float* W_in   = (const float*)d_in[5];
    const float* conv_w = (const float*)d_in[6];
    const float* conv_b = (const float*)d_in[7];
    const float* W_xp   = (const float*)d_in[8];
    const float* W_dt   = (const float*)d_in[9];
    const float* b_dt   = (const float*)d_in[10];
    const float* A_log  = (const float*)d_in[11];
    const float* Dvec   = (const float*)d_in[12];
    const float* W_out  = (const float*)d_in[13];
    float* out = (float*)d_out;

    float* ws = (float*)d_ws;
    float* tokens = ws;  ws += (size_t)LTOK * DIMC;
    float* x_dbl  = ws;  ws += (size_t)LTOK * 64;
    float* chA    = ws;  ws += (size_t)NLANE * NCH;
    float* chB    = ws;  ws += (size_t)NLANE * NCH;
    float* hst    = ws;  ws += (size_t)NLANE * NCH;
    float* Dloc   = ws;  ws += (size_t)LTOK * DI;
    float* o5     = ws;  ws += (size_t)DIMC * LTOK;
    float* A2pre  = ws;  ws += NLANE;
    unsigned short* ytok     = (unsigned short*)ws;  ws += (size_t)LTOK * DIMC / 2;
    unsigned short* yloc     = (unsigned short*)ws;  ws += (size_t)LTOK * DI / 2;
    unsigned short* xsb      = (unsigned short*)ws;  ws += (size_t)LTOK * DI / 2;
    unsigned short* xcb      = (unsigned short*)ws;  ws += (size_t)LTOK * DI / 2;
    unsigned short* zsb      = (unsigned short*)ws;  ws += (size_t)LTOK * DI / 2;
    unsigned short* W_in_bf  = (unsigned short*)ws;  ws += (size_t)768 * 192 / 2;
    unsigned short* W_out_bf = (unsigned short*)ws;  ws += (size_t)192 * 384 / 2;
    unsigned short* W_xp_pad = (unsigned short*)ws;  ws += (size_t)64 * 384 / 2;

    poolln_kernel<<<288, 256, 0, stream>>>(x, ln1_g, ln1_b, W_in, W_out, W_xp, A_log,
                                           tokens, ytok, W_in_bf, W_out_bf, W_xp_pad, A2pre);
    gemm_in<<<dim3(12, 64), 256, 0, stream>>>(ytok, W_in_bf, xcb, zsb);
    convxdbl<<<256, 256, 0, stream>>>(xcb, conv_w, conv_b, W_xp_pad, xsb, x_dbl);
    scan1<<<dim3(6, NCH), 256, 0, stream>>>(x_dbl, xsb, W_dt, b_dt, A2pre, chA, chB, Dloc, yloc);
    scan2p<<<NLANE / 16, 256, 0, stream>>>(chA, chB, hst);
    gemmscanln<<<256, 512, 0, stream>>>(hst, Dloc, x_dbl, A2pre, yloc, xsb, zsb, Dvec,
                                        W_out_bf, tokens, ln2_g, ln2_b, o5);
    upfft<<<3072, 256, 0, stream>>>(o5, x, out);
}